// Round 24
// baseline (7148.792 us; speedup 1.0000x reference)
//
#include <hip/hip_runtime.h>
#include <hip/hip_bf16.h>
#include <math.h>

#define NPTS    16384
#define DIM     128
#define KSEL    16
#define TSEL    18      // per-scanner top list (16 + self + 1 margin)
#define NSC     8       // scanners per row = 2 col-half waves x 4 lane-groups
#define RPB     32      // rows per block (2 row-groups x 16)
#define THREADS 256
#define NT      ((NPTS / 2) / 16)  // 512 candidate tiles per wave
#define CBUF    20      // collect slots per (row, scanner): 18 + tie slack
#define CST2    (NSC * CBUF + 1)   // 161 -> 41216 B LDS
#define NC      (NSC * TSEL)       // 144 (fallback path)
#define CSTRIDE 145                // fallback keys stride
#define PREP    6       // probe repeat factor (real time = dispatch dur / 6)

typedef float f32x4  __attribute__((ext_vector_type(4)));
typedef short bf16x8 __attribute__((ext_vector_type(8)));

__device__ __forceinline__ unsigned short f2b(float f) {
    __hip_bfloat16 h = __float2bfloat16(f);   // RTNE
    return *(unsigned short*)&h;
}

// branchless sorted-insert level (median identity; fuses to v_med3_f32)
#define MED3_LADDER(bv, val)                                   \
    do {                                                       \
        _Pragma("unroll")                                      \
        for (int k = TSEL - 1; k >= 1; --k)                    \
            bv[k] = fminf(bv[k], fmaxf(bv[k - 1], (val)));     \
        bv[0] = fminf(bv[0], (val));                           \
    } while (0)

// BIT-EXACT numpy f32 pairwise-sum of x*x (AVX512 path) — validated R9.
__device__ __forceinline__ float np_sq_avx512(const float* __restrict__ x) {
    float s[16];
    #pragma unroll
    for (int L = 0; L < 16; ++L) {
        const float m0 = __fmul_rn(x[  0 + L], x[  0 + L]);
        const float m1 = __fmul_rn(x[ 16 + L], x[ 16 + L]);
        const float m2 = __fmul_rn(x[ 32 + L], x[ 32 + L]);
        const float m3 = __fmul_rn(x[ 48 + L], x[ 48 + L]);
        const float m4 = __fmul_rn(x[ 64 + L], x[ 64 + L]);
        const float m5 = __fmul_rn(x[ 80 + L], x[ 80 + L]);
        const float m6 = __fmul_rn(x[ 96 + L], x[ 96 + L]);
        const float m7 = __fmul_rn(x[112 + L], x[112 + L]);
        s[L] = __fadd_rn(
            __fadd_rn(__fadd_rn(m0, m1), __fadd_rn(m2, m3)),
            __fadd_rn(__fadd_rn(m4, m5), __fadd_rn(m6, m7)));
    }
    float u[8];
    #pragma unroll
    for (int i = 0; i < 8; ++i) u[i] = __fadd_rn(s[i], s[i + 8]);
    float v[4];
    #pragma unroll
    for (int i = 0; i < 4; ++i) v[i] = __fadd_rn(u[i], u[i + 4]);
    return __fadd_rn(__fadd_rn(v[0], v[2]), __fadd_rn(v[1], v[3]));
}

// scan-phase sq (capture key only)
__device__ __forceinline__ float scan_sq(const float* __restrict__ xp) {
    const float4* x4 = (const float4*)xp;
    float a0 = 0.f, a1 = 0.f, a2 = 0.f, a3 = 0.f;
    #pragma unroll
    for (int g = 0; g < 32; ++g) {
        const float4 b = x4[g];
        a0 += b.x * b.x; a1 += b.y * b.y;
        a2 += b.z * b.z; a3 += b.w * b.w;
    }
    return (a0 + a1) + (a2 + a3);
}

__global__ __launch_bounds__(256)
void sq_kernel(const float* __restrict__ X, float* __restrict__ sqws) {
    const int j = blockIdx.x * 256 + threadIdx.x;
    sqws[j] = 0.5f * scan_sq(X + (size_t)j * DIM);   // half-scale scan key
}

__global__ __launch_bounds__(256)
void cvt_kernel(const float* __restrict__ X, unsigned short* __restrict__ Xb) {
    const size_t i = ((size_t)blockIdx.x * 256 + threadIdx.x) * 8;
    const float4 v0 = *(const float4*)(X + i);
    const float4 v1 = *(const float4*)(X + i + 4);
    ushort4 o0, o1;
    o0.x = f2b(v0.x); o0.y = f2b(v0.y); o0.z = f2b(v0.z); o0.w = f2b(v0.w);
    o1.x = f2b(v1.x); o1.y = f2b(v1.y); o1.z = f2b(v1.z); o1.w = f2b(v1.w);
    *(ushort4*)(Xb + i) = o0;
    *(ushort4*)(Xb + i + 4) = o1;
}

// ===================== DIAGNOSTIC PROBES (write to d_ws) ====================
// probe_mfma: pass-A loads + MFMA only; accs kept live via sum (anti-DCE).
__global__ __launch_bounds__(THREADS, 2)
void probe_mfma(const float* __restrict__ sqws,
                const unsigned short* __restrict__ Xb,
                float* __restrict__ po) {
    const int tid = threadIdx.x;
    const int w = tid >> 6, l = tid & 63, lg = l >> 4, l15 = l & 15;
    const int rloc = (w >> 1) * 16 + l15;
    const int grow = blockIdx.x * RPB + rloc;
    const int colbase = (w & 1) * (NPTS / 2);
    bf16x8 nb[4];
    {
        const unsigned short* xr = Xb + (size_t)grow * DIM + lg * 8;
        #pragma unroll
        for (int m = 0; m < 4; ++m) {
            union { bf16x8 h; uint4 u; } t;
            t.h = *(const bf16x8*)(xr + m * 32);
            t.u.x ^= 0x80008000u; t.u.y ^= 0x80008000u;
            t.u.z ^= 0x80008000u; t.u.w ^= 0x80008000u;
            nb[m] = t.h;
        }
    }
    float s = 0.f;
    #pragma unroll 1
    for (int rep = 0; rep < PREP; ++rep) {
        const unsigned short* ap = Xb + (size_t)(colbase + l15) * DIM + lg * 8;
        #pragma unroll 1
        for (int t = 0; t < NT; t += 2) {
            const int cb = colbase + t * 16;
            const bf16x8 a0 = *(const bf16x8*)(ap);
            const bf16x8 a1 = *(const bf16x8*)(ap + 32);
            const bf16x8 a2 = *(const bf16x8*)(ap + 64);
            const bf16x8 a3 = *(const bf16x8*)(ap + 96);
            const bf16x8 b0 = *(const bf16x8*)(ap + 16 * DIM);
            const bf16x8 b1 = *(const bf16x8*)(ap + 16 * DIM + 32);
            const bf16x8 b2 = *(const bf16x8*)(ap + 16 * DIM + 64);
            const bf16x8 b3 = *(const bf16x8*)(ap + 16 * DIM + 96);
            ap += 32 * DIM;
            f32x4 aA1 = *(const f32x4*)&sqws[cb + lg * 4];
            f32x4 aA2 = {0.f, 0.f, 0.f, 0.f};
            f32x4 aB1 = *(const f32x4*)&sqws[cb + 16 + lg * 4];
            f32x4 aB2 = {0.f, 0.f, 0.f, 0.f};
            aA1 = __builtin_amdgcn_mfma_f32_16x16x32_bf16(a0, nb[0], aA1, 0, 0, 0);
            aA2 = __builtin_amdgcn_mfma_f32_16x16x32_bf16(a2, nb[2], aA2, 0, 0, 0);
            aB1 = __builtin_amdgcn_mfma_f32_16x16x32_bf16(b0, nb[0], aB1, 0, 0, 0);
            aB2 = __builtin_amdgcn_mfma_f32_16x16x32_bf16(b2, nb[2], aB2, 0, 0, 0);
            aA1 = __builtin_amdgcn_mfma_f32_16x16x32_bf16(a1, nb[1], aA1, 0, 0, 0);
            aA2 = __builtin_amdgcn_mfma_f32_16x16x32_bf16(a3, nb[3], aA2, 0, 0, 0);
            aB1 = __builtin_amdgcn_mfma_f32_16x16x32_bf16(b1, nb[1], aB1, 0, 0, 0);
            aB2 = __builtin_amdgcn_mfma_f32_16x16x32_bf16(b3, nb[3], aB2, 0, 0, 0);
            #pragma unroll
            for (int r = 0; r < 4; ++r)
                s += (aA1[r] + aA2[r]) + (aB1[r] + aB2[r]);   // keep-alive
        }
    }
    po[blockIdx.x * THREADS + tid] = s;
}

// probe_ladder: full pass A (loads + MFMA + med3 ladder), writes T.
__global__ __launch_bounds__(THREADS, 2)
void probe_ladder(const float* __restrict__ sqws,
                  const unsigned short* __restrict__ Xb,
                  float* __restrict__ po) {
    const int tid = threadIdx.x;
    const int w = tid >> 6, l = tid & 63, lg = l >> 4, l15 = l & 15;
    const int rloc = (w >> 1) * 16 + l15;
    const int grow = blockIdx.x * RPB + rloc;
    const int colbase = (w & 1) * (NPTS / 2);
    bf16x8 nb[4];
    {
        const unsigned short* xr = Xb + (size_t)grow * DIM + lg * 8;
        #pragma unroll
        for (int m = 0; m < 4; ++m) {
            union { bf16x8 h; uint4 u; } t;
            t.h = *(const bf16x8*)(xr + m * 32);
            t.u.x ^= 0x80008000u; t.u.y ^= 0x80008000u;
            t.u.z ^= 0x80008000u; t.u.w ^= 0x80008000u;
            nb[m] = t.h;
        }
    }
    float bv[TSEL];
    #pragma unroll
    for (int k = 0; k < TSEL; ++k) bv[k] = 3.0e38f;
    #pragma unroll 1
    for (int rep = 0; rep < PREP; ++rep) {
        const unsigned short* ap = Xb + (size_t)(colbase + l15) * DIM + lg * 8;
        #pragma unroll 1
        for (int t = 0; t < NT; t += 2) {
            const int cb = colbase + t * 16;
            const bf16x8 a0 = *(const bf16x8*)(ap);
            const bf16x8 a1 = *(const bf16x8*)(ap + 32);
            const bf16x8 a2 = *(const bf16x8*)(ap + 64);
            const bf16x8 a3 = *(const bf16x8*)(ap + 96);
            const bf16x8 b0 = *(const bf16x8*)(ap + 16 * DIM);
            const bf16x8 b1 = *(const bf16x8*)(ap + 16 * DIM + 32);
            const bf16x8 b2 = *(const bf16x8*)(ap + 16 * DIM + 64);
            const bf16x8 b3 = *(const bf16x8*)(ap + 16 * DIM + 96);
            ap += 32 * DIM;
            f32x4 aA1 = *(const f32x4*)&sqws[cb + lg * 4];
            f32x4 aA2 = {0.f, 0.f, 0.f, 0.f};
            f32x4 aB1 = *(const f32x4*)&sqws[cb + 16 + lg * 4];
            f32x4 aB2 = {0.f, 0.f, 0.f, 0.f};
            aA1 = __builtin_amdgcn_mfma_f32_16x16x32_bf16(a0, nb[0], aA1, 0, 0, 0);
            aA2 = __builtin_amdgcn_mfma_f32_16x16x32_bf16(a2, nb[2], aA2, 0, 0, 0);
            aB1 = __builtin_amdgcn_mfma_f32_16x16x32_bf16(b0, nb[0], aB1, 0, 0, 0);
            aB2 = __builtin_amdgcn_mfma_f32_16x16x32_bf16(b2, nb[2], aB2, 0, 0, 0);
            aA1 = __builtin_amdgcn_mfma_f32_16x16x32_bf16(a1, nb[1], aA1, 0, 0, 0);
            aA2 = __builtin_amdgcn_mfma_f32_16x16x32_bf16(a3, nb[3], aA2, 0, 0, 0);
            aB1 = __builtin_amdgcn_mfma_f32_16x16x32_bf16(b1, nb[1], aB1, 0, 0, 0);
            aB2 = __builtin_amdgcn_mfma_f32_16x16x32_bf16(b3, nb[3], aB2, 0, 0, 0);
            #pragma unroll
            for (int r = 0; r < 4; ++r) {
                const float vA = aA1[r] + aA2[r];
                MED3_LADDER(bv, vA);
            }
            #pragma unroll
            for (int r = 0; r < 4; ++r) {
                const float vB = aB1[r] + aB2[r];
                MED3_LADDER(bv, vB);
            }
        }
    }
    po[blockIdx.x * THREADS + tid] = bv[TSEL - 1];
}

// ================= PRODUCTION PIPELINE (R23 verbatim) =======================
__global__ __launch_bounds__(THREADS, 2)
void knn_twopass(const float* __restrict__ X, const float* __restrict__ sqws,
                 const unsigned short* __restrict__ Xb, int* __restrict__ out) {
    __shared__ unsigned long long cand[RPB * CST2];   // 41216 B

    const int tid  = threadIdx.x;
    const int w    = tid >> 6;
    const int l    = tid & 63;
    const int lg   = l >> 4;
    const int l15  = l & 15;
    const int rloc = (w >> 1) * 16 + l15;
    const int grow = blockIdx.x * RPB + rloc;
    const int colbase = (w & 1) * (NPTS / 2);
    const int sid = (w & 1) * 4 + lg;

    bf16x8 nb[4];
    {
        const unsigned short* xr = Xb + (size_t)grow * DIM + lg * 8;
        #pragma unroll
        for (int m = 0; m < 4; ++m) {
            union { bf16x8 h; uint4 u; } t;
            t.h = *(const bf16x8*)(xr + m * 32);
            t.u.x ^= 0x80008000u; t.u.y ^= 0x80008000u;
            t.u.z ^= 0x80008000u; t.u.w ^= 0x80008000u;
            nb[m] = t.h;
        }
    }

    float bv[TSEL];
    #pragma unroll
    for (int k = 0; k < TSEL; ++k) bv[k] = 3.0e38f;
    {
        const unsigned short* ap = Xb + (size_t)(colbase + l15) * DIM + lg * 8;
        #pragma unroll 1
        for (int t = 0; t < NT; t += 2) {
            const int cb = colbase + t * 16;
            const bf16x8 a0 = *(const bf16x8*)(ap);
            const bf16x8 a1 = *(const bf16x8*)(ap + 32);
            const bf16x8 a2 = *(const bf16x8*)(ap + 64);
            const bf16x8 a3 = *(const bf16x8*)(ap + 96);
            const bf16x8 b0 = *(const bf16x8*)(ap + 16 * DIM);
            const bf16x8 b1 = *(const bf16x8*)(ap + 16 * DIM + 32);
            const bf16x8 b2 = *(const bf16x8*)(ap + 16 * DIM + 64);
            const bf16x8 b3 = *(const bf16x8*)(ap + 16 * DIM + 96);
            ap += 32 * DIM;
            f32x4 aA1 = *(const f32x4*)&sqws[cb + lg * 4];
            f32x4 aA2 = {0.f, 0.f, 0.f, 0.f};
            f32x4 aB1 = *(const f32x4*)&sqws[cb + 16 + lg * 4];
            f32x4 aB2 = {0.f, 0.f, 0.f, 0.f};
            aA1 = __builtin_amdgcn_mfma_f32_16x16x32_bf16(a0, nb[0], aA1, 0, 0, 0);
            aA2 = __builtin_amdgcn_mfma_f32_16x16x32_bf16(a2, nb[2], aA2, 0, 0, 0);
            aB1 = __builtin_amdgcn_mfma_f32_16x16x32_bf16(b0, nb[0], aB1, 0, 0, 0);
            aB2 = __builtin_amdgcn_mfma_f32_16x16x32_bf16(b2, nb[2], aB2, 0, 0, 0);
            aA1 = __builtin_amdgcn_mfma_f32_16x16x32_bf16(a1, nb[1], aA1, 0, 0, 0);
            aA2 = __builtin_amdgcn_mfma_f32_16x16x32_bf16(a3, nb[3], aA2, 0, 0, 0);
            aB1 = __builtin_amdgcn_mfma_f32_16x16x32_bf16(b1, nb[1], aB1, 0, 0, 0);
            aB2 = __builtin_amdgcn_mfma_f32_16x16x32_bf16(b3, nb[3], aB2, 0, 0, 0);
            #pragma unroll
            for (int r = 0; r < 4; ++r) {
                const float vA = aA1[r] + aA2[r];
                MED3_LADDER(bv, vA);
            }
            #pragma unroll
            for (int r = 0; r < 4; ++r) {
                const float vB = aB1[r] + aB2[r];
                MED3_LADDER(bv, vB);
            }
        }
    }
    const float T = bv[TSEL - 1];

    #pragma unroll
    for (int c = 0; c < CBUF; ++c)
        cand[rloc * CST2 + sid * CBUF + c] = 0xFFFFFFFFFFFFFFFFULL;
    {
        int cnt = 0;
        const unsigned short* ap = Xb + (size_t)(colbase + l15) * DIM + lg * 8;
        #pragma unroll 1
        for (int t = 0; t < NT; t += 2) {
            const int cb = colbase + t * 16;
            const bf16x8 a0 = *(const bf16x8*)(ap);
            const bf16x8 a1 = *(const bf16x8*)(ap + 32);
            const bf16x8 a2 = *(const bf16x8*)(ap + 64);
            const bf16x8 a3 = *(const bf16x8*)(ap + 96);
            const bf16x8 b0 = *(const bf16x8*)(ap + 16 * DIM);
            const bf16x8 b1 = *(const bf16x8*)(ap + 16 * DIM + 32);
            const bf16x8 b2 = *(const bf16x8*)(ap + 16 * DIM + 64);
            const bf16x8 b3 = *(const bf16x8*)(ap + 16 * DIM + 96);
            ap += 32 * DIM;
            f32x4 aA1 = *(const f32x4*)&sqws[cb + lg * 4];
            f32x4 aA2 = {0.f, 0.f, 0.f, 0.f};
            f32x4 aB1 = *(const f32x4*)&sqws[cb + 16 + lg * 4];
            f32x4 aB2 = {0.f, 0.f, 0.f, 0.f};
            aA1 = __builtin_amdgcn_mfma_f32_16x16x32_bf16(a0, nb[0], aA1, 0, 0, 0);
            aA2 = __builtin_amdgcn_mfma_f32_16x16x32_bf16(a2, nb[2], aA2, 0, 0, 0);
            aB1 = __builtin_amdgcn_mfma_f32_16x16x32_bf16(b0, nb[0], aB1, 0, 0, 0);
            aB2 = __builtin_amdgcn_mfma_f32_16x16x32_bf16(b2, nb[2], aB2, 0, 0, 0);
            aA1 = __builtin_amdgcn_mfma_f32_16x16x32_bf16(a1, nb[1], aA1, 0, 0, 0);
            aA2 = __builtin_amdgcn_mfma_f32_16x16x32_bf16(a3, nb[3], aA2, 0, 0, 0);
            aB1 = __builtin_amdgcn_mfma_f32_16x16x32_bf16(b1, nb[1], aB1, 0, 0, 0);
            aB2 = __builtin_amdgcn_mfma_f32_16x16x32_bf16(b3, nb[3], aB2, 0, 0, 0);
            #pragma unroll
            for (int r = 0; r < 4; ++r) {
                const float vA = aA1[r] + aA2[r];
                if (vA <= T && cnt < CBUF) {
                    cand[rloc * CST2 + sid * CBUF + cnt] =
                        (unsigned long long)(unsigned int)(cb + lg * 4 + r);
                    ++cnt;
                }
            }
            #pragma unroll
            for (int r = 0; r < 4; ++r) {
                const float vB = aB1[r] + aB2[r];
                if (vB <= T && cnt < CBUF) {
                    cand[rloc * CST2 + sid * CBUF + cnt] =
                        (unsigned long long)(unsigned int)(cb + 16 + lg * 4 + r);
                    ++cnt;
                }
            }
        }
    }

    float4 xi4[32];
    {
        const float4* xr = (const float4*)(X + (size_t)grow * DIM);
        #pragma unroll
        for (int g = 0; g < 32; ++g) xi4[g] = xr[g];
    }
    const float sqi32 = np_sq_avx512(X + (size_t)grow * DIM);

    #pragma unroll 1
    for (int k = 0; k < CBUF; ++k) {
        const int slot = rloc * CST2 + sid * CBUF + k;
        const unsigned long long j64 = cand[slot];
        if (j64 == 0xFFFFFFFFFFFFFFFFULL) continue;
        const int j = (int)j64;
        if (j == grow) {
            cand[slot] = 0xFFFFFFFFFFFFFFFFULL;
        } else {
            const float* xjp = X + (size_t)j * DIM;
            const float4* xj = (const float4*)xjp;
            const float sqj32 = np_sq_avx512(xjp);
            float cacc = 0.f;
            #pragma unroll
            for (int g = 0; g < 32; ++g) {
                const float4 a = xi4[g], b = xj[g];
                cacc = __fmaf_rn(a.x, b.x, cacc);
                cacc = __fmaf_rn(a.y, b.y, cacc);
                cacc = __fmaf_rn(a.z, b.z, cacc);
                cacc = __fmaf_rn(a.w, b.w, cacc);
            }
            float d2c = __fsub_rn(__fadd_rn(sqi32, sqj32),
                                  __fmul_rn(2.0f, cacc));
            if (d2c < 0.0f) d2c = 0.0f;
            const float dist32 = sqrtf(d2c);
            cand[slot] = ((unsigned long long)__float_as_uint(dist32) << 32)
                         | (unsigned int)j;
        }
    }
    __syncthreads();

    if (tid < RPB) {
        const int base = tid * CST2;
        const int i = blockIdx.x * RPB + tid;
        for (int m = 0; m < KSEL; ++m) {
            unsigned long long best = 0xFFFFFFFFFFFFFFFFULL; int bc = 0;
            for (int c2 = 0; c2 < NSC * CBUF; ++c2) {
                const unsigned long long v = cand[base + c2];
                if (v < best) { best = v; bc = c2; }
            }
            out[(size_t)i * KSEL + m] = (int)(best & 0xFFFFFFFFULL);
            cand[base + bc] = 0xFFFFFFFFFFFFFFFFULL;
        }
    }
}

// ---- fallback monolith (R14 verbatim, proven; used only without ws) ----
__global__ __launch_bounds__(THREADS, 2)
void knn_mono(const float* __restrict__ X, int* __restrict__ out) {
    __shared__ __align__(16) char smem[NPTS * 4];
    float* sqh = (float*)smem;
    unsigned long long* keys = (unsigned long long*)smem;
    const int tid = threadIdx.x;
    const int w = tid >> 6, l = tid & 63, lg = l >> 4, l15 = l & 15;
    const int rloc = (w >> 1) * 16 + l15;
    const int grow = blockIdx.x * RPB + rloc;
    const int colbase = (w & 1) * (NPTS / 2);
    const int s = (w & 1) * 4 + lg;
    #pragma unroll 1
    for (int q = 0; q < NPTS / THREADS; ++q) {
        const int j = tid + THREADS * q;
        sqh[j] = 0.5f * scan_sq(X + (size_t)j * DIM);
    }
    __syncthreads();
    bf16x8 nb[4];
    {
        const float* xr = X + (size_t)grow * DIM + lg * 8;
        #pragma unroll
        for (int m = 0; m < 4; ++m) {
            bf16x8 h;
            #pragma unroll
            for (int e = 0; e < 8; ++e) h[e] = (short)f2b(-xr[m * 32 + e]);
            nb[m] = h;
        }
    }
    float bv[TSEL]; int bi[TSEL];
    #pragma unroll
    for (int k = 0; k < TSEL; ++k) { bv[k] = 3.0e38f; bi[k] = 0; }
    const float* apf = X + (size_t)(colbase + l15) * DIM + lg * 8;
    #pragma unroll 1
    for (int t = 0; t < NT; ++t) {
        const int cb = colbase + t * 16;
        bf16x8 a0, a1, a2, a3;
        #pragma unroll
        for (int e = 0; e < 8; ++e) {
            a0[e] = (short)f2b(apf[e]);
            a1[e] = (short)f2b(apf[32 + e]);
            a2[e] = (short)f2b(apf[64 + e]);
            a3[e] = (short)f2b(apf[96 + e]);
        }
        apf += 16 * DIM;
        f32x4 acc = *(const f32x4*)&sqh[cb + lg * 4];
        acc = __builtin_amdgcn_mfma_f32_16x16x32_bf16(a0, nb[0], acc, 0, 0, 0);
        acc = __builtin_amdgcn_mfma_f32_16x16x32_bf16(a1, nb[1], acc, 0, 0, 0);
        acc = __builtin_amdgcn_mfma_f32_16x16x32_bf16(a2, nb[2], acc, 0, 0, 0);
        acc = __builtin_amdgcn_mfma_f32_16x16x32_bf16(a3, nb[3], acc, 0, 0, 0);
        #pragma unroll
        for (int r = 0; r < 4; ++r) {
            const float val = acc[r];
            if (val < bv[TSEL - 1]) {
                const int jg = cb + lg * 4 + r;
                #pragma unroll
                for (int k = TSEL - 1; k >= 1; --k) {
                    const bool m1 = val < bv[k - 1];
                    const bool m2 = val < bv[k];
                    bv[k] = m1 ? bv[k - 1] : (m2 ? val : bv[k]);
                    bi[k] = m1 ? bi[k - 1] : (m2 ? jg  : bi[k]);
                }
                if (val < bv[0]) { bv[0] = val; bi[0] = jg; }
            }
        }
    }
    __syncthreads();
    float4 xi4[32];
    {
        const float4* xr = (const float4*)(X + (size_t)grow * DIM);
        #pragma unroll
        for (int g = 0; g < 32; ++g) xi4[g] = xr[g];
    }
    const float sqi32 = np_sq_avx512(X + (size_t)grow * DIM);
    #pragma unroll
    for (int k = 0; k < TSEL; ++k) {
        const int j = bi[k];
        unsigned long long key;
        if (j == grow) {
            key = 0xFFFFFFFFFFFFFFFFULL;
        } else {
            const float* xjp = X + (size_t)j * DIM;
            const float4* xj = (const float4*)xjp;
            const float sqj32 = np_sq_avx512(xjp);
            float cacc = 0.f;
            #pragma unroll
            for (int g = 0; g < 32; ++g) {
                const float4 a = xi4[g], b = xj[g];
                cacc = __fmaf_rn(a.x, b.x, cacc);
                cacc = __fmaf_rn(a.y, b.y, cacc);
                cacc = __fmaf_rn(a.z, b.z, cacc);
                cacc = __fmaf_rn(a.w, b.w, cacc);
            }
            float d2c = __fsub_rn(__fadd_rn(sqi32, sqj32),
                                  __fmul_rn(2.0f, cacc));
            if (d2c < 0.0f) d2c = 0.0f;
            const float dist32 = sqrtf(d2c);
            key = ((unsigned long long)__float_as_uint(dist32) << 32)
                  | (unsigned int)j;
        }
        keys[rloc * CSTRIDE + s * TSEL + k] = key;
    }
    __syncthreads();
    if (tid < RPB) {
        const int base = tid * CSTRIDE;
        const int i = blockIdx.x * RPB + tid;
        for (int m = 0; m < KSEL; ++m) {
            unsigned long long best = 0xFFFFFFFFFFFFFFFFULL; int bc = 0;
            for (int c2 = 0; c2 < NC; ++c2) {
                const unsigned long long v = keys[base + c2];
                if (v < best) { best = v; bc = c2; }
            }
            out[(size_t)i * KSEL + m] = (int)(best & 0xFFFFFFFFULL);
            keys[base + bc] = 0xFFFFFFFFFFFFFFFFULL;
        }
    }
}

extern "C" void kernel_launch(void* const* d_in, const int* in_sizes, int n_in,
                              void* d_out, int out_size, void* d_ws, size_t ws_size,
                              hipStream_t stream) {
    (void)in_sizes; (void)n_in; (void)out_size;
    const float* X = (const float*)d_in[0];
    int* out = (int*)d_out;
    const size_t sqB = (size_t)NPTS * 4;             // 64 KB
    const size_t xbB = (size_t)NPTS * DIM * 2;       // 4.19 MB
    const size_t probeB = (size_t)(NPTS / RPB) * THREADS * 4;  // 512 KB
    float* sqws = (float*)d_ws;
    unsigned short* Xb = (unsigned short*)((char*)d_ws + sqB);
    float* po = (float*)((char*)d_ws + sqB + xbB);
    if (ws_size >= sqB + xbB + probeB) {
        sq_kernel<<<dim3(NPTS / 256), dim3(256), 0, stream>>>(X, sqws);
        cvt_kernel<<<dim3(NPTS * DIM / 8 / 256), dim3(256), 0, stream>>>(X, Xb);
        // diagnostic probes (results discarded; durations read via rocprof)
        probe_mfma<<<dim3(NPTS / RPB), dim3(THREADS), 0, stream>>>(sqws, Xb, po);
        probe_ladder<<<dim3(NPTS / RPB), dim3(THREADS), 0, stream>>>(sqws, Xb, po);
        knn_twopass<<<dim3(NPTS / RPB), dim3(THREADS), 0, stream>>>(X, sqws, Xb, out);
    } else if (ws_size >= sqB + xbB) {
        sq_kernel<<<dim3(NPTS / 256), dim3(256), 0, stream>>>(X, sqws);
        cvt_kernel<<<dim3(NPTS * DIM / 8 / 256), dim3(256), 0, stream>>>(X, Xb);
        knn_twopass<<<dim3(NPTS / RPB), dim3(THREADS), 0, stream>>>(X, sqws, Xb, out);
    } else {
        knn_mono<<<dim3(NPTS / RPB), dim3(THREADS), 0, stream>>>(X, out);
    }
}

// Round 25
// 951.184 us; speedup vs baseline: 7.5157x; 7.5157x over previous
//
#include <hip/hip_runtime.h>
#include <hip/hip_bf16.h>
#include <math.h>

#define NPTS    16384
#define DIM     128
#define KSEL    16
#define TSEL    18      // per-scanner top list (16 + self + 1 margin)
#define NSC     8       // scanners per row = 2 col-half waves x 4 lane-groups
#define RPB     32      // rows per block (2 row-groups x 16)
#define THREADS 256
#define NT      ((NPTS / 2) / 16)  // 512 candidate tiles per wave
#define NC      (NSC * TSEL)       // 144 candidates per row
#define CSTRIDE 145                // padded per-row stride (u64 keys)
#define IDXMASK 0x3FFFu            // 14-bit candidate index (NPTS/2 = 8192 span
                                   // per half, global idx < 16384 fits)

typedef float f32x4  __attribute__((ext_vector_type(4)));
typedef short bf16x8 __attribute__((ext_vector_type(8)));

__device__ __forceinline__ unsigned short f2b(float f) {
    __hip_bfloat16 h = __float2bfloat16(f);   // RTNE
    return *(unsigned short*)&h;
}

// branchless sorted-insert level (median identity; fuses to v_med3_f32)
#define MED3_LADDER(bv, val)                                   \
    do {                                                       \
        _Pragma("unroll")                                      \
        for (int k = TSEL - 1; k >= 1; --k)                    \
            bv[k] = fminf(bv[k], fmaxf(bv[k - 1], (val)));     \
        bv[0] = fminf(bv[0], (val));                           \
    } while (0)

// pack candidate index into low 14 mantissa bits of the f32 scan key.
// Perturbation <= |val| * 2^-9 ~ 0.13 -- far inside the validated capture
// margin (bf16 noise sigma 0.06 already absorbed; local ranks of true
// targets are ~2-6 vs TSEL=18). Packed value is still an ordinary float,
// so the med3 ladder works unchanged; idx comes back free at extraction.
__device__ __forceinline__ float packkey(float val, int jg) {
    const unsigned int u =
        (__float_as_uint(val) & 0xFFFFC000u) | (unsigned int)(jg & 0x3FFF);
    return __uint_as_float(u);
}

// BIT-EXACT numpy f32 pairwise-sum of x*x (AVX512 path) — validated R9.
__device__ __forceinline__ float np_sq_avx512(const float* __restrict__ x) {
    float s[16];
    #pragma unroll
    for (int L = 0; L < 16; ++L) {
        const float m0 = __fmul_rn(x[  0 + L], x[  0 + L]);
        const float m1 = __fmul_rn(x[ 16 + L], x[ 16 + L]);
        const float m2 = __fmul_rn(x[ 32 + L], x[ 32 + L]);
        const float m3 = __fmul_rn(x[ 48 + L], x[ 48 + L]);
        const float m4 = __fmul_rn(x[ 64 + L], x[ 64 + L]);
        const float m5 = __fmul_rn(x[ 80 + L], x[ 80 + L]);
        const float m6 = __fmul_rn(x[ 96 + L], x[ 96 + L]);
        const float m7 = __fmul_rn(x[112 + L], x[112 + L]);
        s[L] = __fadd_rn(
            __fadd_rn(__fadd_rn(m0, m1), __fadd_rn(m2, m3)),
            __fadd_rn(__fadd_rn(m4, m5), __fadd_rn(m6, m7)));
    }
    float u[8];
    #pragma unroll
    for (int i = 0; i < 8; ++i) u[i] = __fadd_rn(s[i], s[i + 8]);
    float v[4];
    #pragma unroll
    for (int i = 0; i < 4; ++i) v[i] = __fadd_rn(u[i], u[i + 4]);
    return __fadd_rn(__fadd_rn(v[0], v[2]), __fadd_rn(v[1], v[3]));
}

// scan-phase sq (capture key only)
__device__ __forceinline__ float scan_sq(const float* __restrict__ xp) {
    const float4* x4 = (const float4*)xp;
    float a0 = 0.f, a1 = 0.f, a2 = 0.f, a3 = 0.f;
    #pragma unroll
    for (int g = 0; g < 32; ++g) {
        const float4 b = x4[g];
        a0 += b.x * b.x; a1 += b.y * b.y;
        a2 += b.z * b.z; a3 += b.w * b.w;
    }
    return (a0 + a1) + (a2 + a3);
}

__global__ __launch_bounds__(256)
void sq_kernel(const float* __restrict__ X, float* __restrict__ sqws) {
    const int j = blockIdx.x * 256 + threadIdx.x;
    sqws[j] = 0.5f * scan_sq(X + (size_t)j * DIM);   // half-scale scan key
}

__global__ __launch_bounds__(256)
void cvt_kernel(const float* __restrict__ X, unsigned short* __restrict__ Xb) {
    const size_t i = ((size_t)blockIdx.x * 256 + threadIdx.x) * 8;
    const float4 v0 = *(const float4*)(X + i);
    const float4 v1 = *(const float4*)(X + i + 4);
    ushort4 o0, o1;
    o0.x = f2b(v0.x); o0.y = f2b(v0.y); o0.z = f2b(v0.z); o0.w = f2b(v0.w);
    o1.x = f2b(v1.x); o1.y = f2b(v1.y); o1.z = f2b(v1.z); o1.w = f2b(v1.w);
    *(ushort4*)(Xb + i) = o0;
    *(ushort4*)(Xb + i + 4) = o1;
}

// Single-pass scan with index-packed f32 keys (pass B eliminated — R24
// probes showed the scan stream was paid twice, ~510 us each). Ladder cost
// unchanged; indices extracted from mantissa bits after the scan.
// (256,2)/128-reg operating point (only proven spill-free regime).
__global__ __launch_bounds__(THREADS, 2)
void knn_packed(const float* __restrict__ X, const float* __restrict__ sqws,
                const unsigned short* __restrict__ Xb, int* __restrict__ out) {
    __shared__ unsigned long long keys[RPB * CSTRIDE];   // 37120 B

    const int tid  = threadIdx.x;
    const int w    = tid >> 6;        // wave 0..3
    const int l    = tid & 63;        // lane
    const int lg   = l >> 4;          // lane-group 0..3
    const int l15  = l & 15;
    const int rloc = (w >> 1) * 16 + l15;           // local row 0..31
    const int grow = blockIdx.x * RPB + rloc;       // global query row
    const int colbase = (w & 1) * (NPTS / 2);       // column half
    const int sid = (w & 1) * 4 + lg;               // scanner 0..7

    // ---- B fragments: NEGATED query row (validated R13+) ----
    bf16x8 nb[4];
    {
        const unsigned short* xr = Xb + (size_t)grow * DIM + lg * 8;
        #pragma unroll
        for (int m = 0; m < 4; ++m) {
            union { bf16x8 h; uint4 u; } t;
            t.h = *(const bf16x8*)(xr + m * 32);
            t.u.x ^= 0x80008000u; t.u.y ^= 0x80008000u;
            t.u.z ^= 0x80008000u; t.u.w ^= 0x80008000u;
            nb[m] = t.h;
        }
    }

    // ---- single pass: top-TSEL of packed keys, 2 tiles/iter ----
    float bv[TSEL];
    #pragma unroll
    for (int k = 0; k < TSEL; ++k) bv[k] = 3.0e38f;
    {
        const unsigned short* ap = Xb + (size_t)(colbase + l15) * DIM + lg * 8;
        #pragma unroll 1
        for (int t = 0; t < NT; t += 2) {
            const int cb = colbase + t * 16;
            // 8 fragment loads for two tiles (max MLP at iteration head)
            const bf16x8 a0 = *(const bf16x8*)(ap);
            const bf16x8 a1 = *(const bf16x8*)(ap + 32);
            const bf16x8 a2 = *(const bf16x8*)(ap + 64);
            const bf16x8 a3 = *(const bf16x8*)(ap + 96);
            const bf16x8 b0 = *(const bf16x8*)(ap + 16 * DIM);
            const bf16x8 b1 = *(const bf16x8*)(ap + 16 * DIM + 32);
            const bf16x8 b2 = *(const bf16x8*)(ap + 16 * DIM + 64);
            const bf16x8 b3 = *(const bf16x8*)(ap + 16 * DIM + 96);
            ap += 32 * DIM;
            // 4 independent 2-deep MFMA chains
            f32x4 aA1 = *(const f32x4*)&sqws[cb + lg * 4];
            f32x4 aA2 = {0.f, 0.f, 0.f, 0.f};
            f32x4 aB1 = *(const f32x4*)&sqws[cb + 16 + lg * 4];
            f32x4 aB2 = {0.f, 0.f, 0.f, 0.f};
            aA1 = __builtin_amdgcn_mfma_f32_16x16x32_bf16(a0, nb[0], aA1, 0, 0, 0);
            aA2 = __builtin_amdgcn_mfma_f32_16x16x32_bf16(a2, nb[2], aA2, 0, 0, 0);
            aB1 = __builtin_amdgcn_mfma_f32_16x16x32_bf16(b0, nb[0], aB1, 0, 0, 0);
            aB2 = __builtin_amdgcn_mfma_f32_16x16x32_bf16(b2, nb[2], aB2, 0, 0, 0);
            aA1 = __builtin_amdgcn_mfma_f32_16x16x32_bf16(a1, nb[1], aA1, 0, 0, 0);
            aA2 = __builtin_amdgcn_mfma_f32_16x16x32_bf16(a3, nb[3], aA2, 0, 0, 0);
            aB1 = __builtin_amdgcn_mfma_f32_16x16x32_bf16(b1, nb[1], aB1, 0, 0, 0);
            aB2 = __builtin_amdgcn_mfma_f32_16x16x32_bf16(b3, nb[3], aB2, 0, 0, 0);
            // packed-key med3 inserts (8 values)
            #pragma unroll
            for (int r = 0; r < 4; ++r) {
                const float pA = packkey(aA1[r] + aA2[r], cb + lg * 4 + r);
                MED3_LADDER(bv, pA);
            }
            #pragma unroll
            for (int r = 0; r < 4; ++r) {
                const float pB = packkey(aB1[r] + aB2[r], cb + 16 + lg * 4 + r);
                MED3_LADDER(bv, pB);
            }
        }
    }

    // ---- rescore the TSEL extracted indices: bit-replica np f32 pipeline --
    float4 xi4[32];
    {
        const float4* xr = (const float4*)(X + (size_t)grow * DIM);
        #pragma unroll
        for (int g = 0; g < 32; ++g) xi4[g] = xr[g];
    }
    const float sqi32 = np_sq_avx512(X + (size_t)grow * DIM);

    #pragma unroll
    for (int k = 0; k < TSEL; ++k) {
        // idx lives in the low 14 bits of the packed key; the half base is
        // implied by this wave's column half (idx < 16384 fits 14 bits only
        // because colbase half-offset occupies bit 13: 0x3FFF covers 0..16383
        // minus nothing — jg & 0x3FFF loses bit 14+; restore explicitly).
        const int jlow = (int)(__float_as_uint(bv[k]) & IDXMASK);
        // jg in [colbase, colbase + 8192); colbase is 0 or 8192 = 0x2000<<1.
        // 14 bits cover 0..16383, and jg < 16384, so jlow IS jg. (8192 needs
        // 14 bits: 0x2000 fits in 0x3FFF.)
        const int j = jlow;
        unsigned long long key;
        if (j == grow) {
            key = 0xFFFFFFFFFFFFFFFFULL;              // self: excluded
        } else {
            const float* xjp = X + (size_t)j * DIM;
            const float4* xj = (const float4*)xjp;
            const float sqj32 = np_sq_avx512(xjp);
            float cacc = 0.f;
            #pragma unroll
            for (int g = 0; g < 32; ++g) {
                const float4 a = xi4[g], b = xj[g];
                cacc = __fmaf_rn(a.x, b.x, cacc);
                cacc = __fmaf_rn(a.y, b.y, cacc);
                cacc = __fmaf_rn(a.z, b.z, cacc);
                cacc = __fmaf_rn(a.w, b.w, cacc);
            }
            float d2c = __fsub_rn(__fadd_rn(sqi32, sqj32),
                                  __fmul_rn(2.0f, cacc));
            if (d2c < 0.0f) d2c = 0.0f;
            const float dist32 = sqrtf(d2c);          // f32 sqrt, correct rnd
            key = ((unsigned long long)__float_as_uint(dist32) << 32)
                  | (unsigned int)j;
        }
        keys[rloc * CSTRIDE + sid * TSEL + k] = key;
    }
    __syncthreads();

    // ---- per-row top-16 by packed u64 key (serial, validated) ----
    if (tid < RPB) {
        const int base = tid * CSTRIDE;
        const int i = blockIdx.x * RPB + tid;
        for (int m = 0; m < KSEL; ++m) {
            unsigned long long best = 0xFFFFFFFFFFFFFFFFULL; int bc = 0;
            for (int c2 = 0; c2 < NC; ++c2) {
                const unsigned long long v = keys[base + c2];
                if (v < best) { best = v; bc = c2; }
            }
            out[(size_t)i * KSEL + m] = (int)(best & 0xFFFFFFFFULL);
            keys[base + bc] = 0xFFFFFFFFFFFFFFFFULL;  // remove picked
        }
    }
}

// ---- fallback monolith (R14 verbatim, proven; used only without ws) ----
__global__ __launch_bounds__(THREADS, 2)
void knn_mono(const float* __restrict__ X, int* __restrict__ out) {
    __shared__ __align__(16) char smem[NPTS * 4];
    float* sqh = (float*)smem;
    unsigned long long* keys = (unsigned long long*)smem;
    const int tid = threadIdx.x;
    const int w = tid >> 6, l = tid & 63, lg = l >> 4, l15 = l & 15;
    const int rloc = (w >> 1) * 16 + l15;
    const int grow = blockIdx.x * RPB + rloc;
    const int colbase = (w & 1) * (NPTS / 2);
    const int s = (w & 1) * 4 + lg;
    #pragma unroll 1
    for (int q = 0; q < NPTS / THREADS; ++q) {
        const int j = tid + THREADS * q;
        sqh[j] = 0.5f * scan_sq(X + (size_t)j * DIM);
    }
    __syncthreads();
    bf16x8 nb[4];
    {
        const float* xr = X + (size_t)grow * DIM + lg * 8;
        #pragma unroll
        for (int m = 0; m < 4; ++m) {
            bf16x8 h;
            #pragma unroll
            for (int e = 0; e < 8; ++e) h[e] = (short)f2b(-xr[m * 32 + e]);
            nb[m] = h;
        }
    }
    float bv[TSEL]; int bi[TSEL];
    #pragma unroll
    for (int k = 0; k < TSEL; ++k) { bv[k] = 3.0e38f; bi[k] = 0; }
    const float* apf = X + (size_t)(colbase + l15) * DIM + lg * 8;
    #pragma unroll 1
    for (int t = 0; t < NT; ++t) {
        const int cb = colbase + t * 16;
        bf16x8 a0, a1, a2, a3;
        #pragma unroll
        for (int e = 0; e < 8; ++e) {
            a0[e] = (short)f2b(apf[e]);
            a1[e] = (short)f2b(apf[32 + e]);
            a2[e] = (short)f2b(apf[64 + e]);
            a3[e] = (short)f2b(apf[96 + e]);
        }
        apf += 16 * DIM;
        f32x4 acc = *(const f32x4*)&sqh[cb + lg * 4];
        acc = __builtin_amdgcn_mfma_f32_16x16x32_bf16(a0, nb[0], acc, 0, 0, 0);
        acc = __builtin_amdgcn_mfma_f32_16x16x32_bf16(a1, nb[1], acc, 0, 0, 0);
        acc = __builtin_amdgcn_mfma_f32_16x16x32_bf16(a2, nb[2], acc, 0, 0, 0);
        acc = __builtin_amdgcn_mfma_f32_16x16x32_bf16(a3, nb[3], acc, 0, 0, 0);
        #pragma unroll
        for (int r = 0; r < 4; ++r) {
            const float val = acc[r];
            if (val < bv[TSEL - 1]) {
                const int jg = cb + lg * 4 + r;
                #pragma unroll
                for (int k = TSEL - 1; k >= 1; --k) {
                    const bool m1 = val < bv[k - 1];
                    const bool m2 = val < bv[k];
                    bv[k] = m1 ? bv[k - 1] : (m2 ? val : bv[k]);
                    bi[k] = m1 ? bi[k - 1] : (m2 ? jg  : bi[k]);
                }
                if (val < bv[0]) { bv[0] = val; bi[0] = jg; }
            }
        }
    }
    __syncthreads();
    float4 xi4[32];
    {
        const float4* xr = (const float4*)(X + (size_t)grow * DIM);
        #pragma unroll
        for (int g = 0; g < 32; ++g) xi4[g] = xr[g];
    }
    const float sqi32 = np_sq_avx512(X + (size_t)grow * DIM);
    #pragma unroll
    for (int k = 0; k < TSEL; ++k) {
        const int j = bi[k];
        unsigned long long key;
        if (j == grow) {
            key = 0xFFFFFFFFFFFFFFFFULL;
        } else {
            const float* xjp = X + (size_t)j * DIM;
            const float4* xj = (const float4*)xjp;
            const float sqj32 = np_sq_avx512(xjp);
            float cacc = 0.f;
            #pragma unroll
            for (int g = 0; g < 32; ++g) {
                const float4 a = xi4[g], b = xj[g];
                cacc = __fmaf_rn(a.x, b.x, cacc);
                cacc = __fmaf_rn(a.y, b.y, cacc);
                cacc = __fmaf_rn(a.z, b.z, cacc);
                cacc = __fmaf_rn(a.w, b.w, cacc);
            }
            float d2c = __fsub_rn(__fadd_rn(sqi32, sqj32),
                                  __fmul_rn(2.0f, cacc));
            if (d2c < 0.0f) d2c = 0.0f;
            const float dist32 = sqrtf(d2c);
            key = ((unsigned long long)__float_as_uint(dist32) << 32)
                  | (unsigned int)j;
        }
        keys[rloc * CSTRIDE + s * TSEL + k] = key;
    }
    __syncthreads();
    if (tid < RPB) {
        const int base = tid * CSTRIDE;
        const int i = blockIdx.x * RPB + tid;
        for (int m = 0; m < KSEL; ++m) {
            unsigned long long best = 0xFFFFFFFFFFFFFFFFULL; int bc = 0;
            for (int c2 = 0; c2 < NC; ++c2) {
                const unsigned long long v = keys[base + c2];
                if (v < best) { best = v; bc = c2; }
            }
            out[(size_t)i * KSEL + m] = (int)(best & 0xFFFFFFFFULL);
            keys[base + bc] = 0xFFFFFFFFFFFFFFFFULL;
        }
    }
}

extern "C" void kernel_launch(void* const* d_in, const int* in_sizes, int n_in,
                              void* d_out, int out_size, void* d_ws, size_t ws_size,
                              hipStream_t stream) {
    (void)in_sizes; (void)n_in; (void)out_size;
    const float* X = (const float*)d_in[0];
    int* out = (int*)d_out;
    const size_t WS_NEED = (size_t)NPTS * 4 + (size_t)NPTS * DIM * 2;  // 4.26MB
    if (ws_size >= WS_NEED) {   // proven available R13-R24
        float* sqws = (float*)d_ws;
        unsigned short* Xb = (unsigned short*)((char*)d_ws + (size_t)NPTS * 4);
        sq_kernel<<<dim3(NPTS / 256), dim3(256), 0, stream>>>(X, sqws);
        cvt_kernel<<<dim3(NPTS * DIM / 8 / 256), dim3(256), 0, stream>>>(X, Xb);
        knn_packed<<<dim3(NPTS / RPB), dim3(THREADS), 0, stream>>>(X, sqws, Xb, out);
    } else {
        knn_mono<<<dim3(NPTS / RPB), dim3(THREADS), 0, stream>>>(X, out);
    }
}

// Round 26
// 607.583 us; speedup vs baseline: 11.7659x; 1.5655x over previous
//
#include <hip/hip_runtime.h>
#include <hip/hip_bf16.h>
#include <math.h>

#define NPTS    16384
#define DIM     128
#define KSEL    16
#define TSEL    18      // per-scanner top list
#define NSC     8       // scanners per row = 2 col-half waves x 4 lane-groups
#define RPB     32      // rows per block (2 row-groups x 16)
#define THREADS 256
#define NT      ((NPTS / 2) / 16)  // 512 candidate tiles per wave
#define RESC    32      // row-wide rescored candidates (self + 31; margin ~15)
#define SKSTR   145     // u32 scan-key stride per row (144 + pad)
#define NC      (NSC * TSEL)       // 144 (fallback path)
#define CSTRIDE 145                // fallback keys stride
#define IDXMASK 0x3FFFu

typedef float f32x4  __attribute__((ext_vector_type(4)));
typedef short bf16x8 __attribute__((ext_vector_type(8)));

__device__ __forceinline__ unsigned short f2b(float f) {
    __hip_bfloat16 h = __float2bfloat16(f);   // RTNE
    return *(unsigned short*)&h;
}

// branchless sorted-insert level (median identity; fuses to v_med3_f32)
#define MED3_LADDER(bv, val)                                   \
    do {                                                       \
        _Pragma("unroll")                                      \
        for (int k = TSEL - 1; k >= 1; --k)                    \
            bv[k] = fminf(bv[k], fmaxf(bv[k - 1], (val)));     \
        bv[0] = fminf(bv[0], (val));                           \
    } while (0)

// pack candidate index into low 14 mantissa bits of the f32 scan key
// (validated R25: perturbation <= |val|*2^-9 ~ 0.13, inside capture margin)
__device__ __forceinline__ float packkey(float val, int jg) {
    const unsigned int u =
        (__float_as_uint(val) & 0xFFFFC000u) | (unsigned int)(jg & 0x3FFF);
    return __uint_as_float(u);
}

// BIT-EXACT numpy f32 pairwise-sum of x*x (AVX512 path) — validated R9.
__device__ __forceinline__ float np_sq_avx512(const float* __restrict__ x) {
    float s[16];
    #pragma unroll
    for (int L = 0; L < 16; ++L) {
        const float m0 = __fmul_rn(x[  0 + L], x[  0 + L]);
        const float m1 = __fmul_rn(x[ 16 + L], x[ 16 + L]);
        const float m2 = __fmul_rn(x[ 32 + L], x[ 32 + L]);
        const float m3 = __fmul_rn(x[ 48 + L], x[ 48 + L]);
        const float m4 = __fmul_rn(x[ 64 + L], x[ 64 + L]);
        const float m5 = __fmul_rn(x[ 80 + L], x[ 80 + L]);
        const float m6 = __fmul_rn(x[ 96 + L], x[ 96 + L]);
        const float m7 = __fmul_rn(x[112 + L], x[112 + L]);
        s[L] = __fadd_rn(
            __fadd_rn(__fadd_rn(m0, m1), __fadd_rn(m2, m3)),
            __fadd_rn(__fadd_rn(m4, m5), __fadd_rn(m6, m7)));
    }
    float u[8];
    #pragma unroll
    for (int i = 0; i < 8; ++i) u[i] = __fadd_rn(s[i], s[i + 8]);
    float v[4];
    #pragma unroll
    for (int i = 0; i < 4; ++i) v[i] = __fadd_rn(u[i], u[i + 4]);
    return __fadd_rn(__fadd_rn(v[0], v[2]), __fadd_rn(v[1], v[3]));
}

// scan-phase sq (capture key only)
__device__ __forceinline__ float scan_sq(const float* __restrict__ xp) {
    const float4* x4 = (const float4*)xp;
    float a0 = 0.f, a1 = 0.f, a2 = 0.f, a3 = 0.f;
    #pragma unroll
    for (int g = 0; g < 32; ++g) {
        const float4 b = x4[g];
        a0 += b.x * b.x; a1 += b.y * b.y;
        a2 += b.z * b.z; a3 += b.w * b.w;
    }
    return (a0 + a1) + (a2 + a3);
}

__global__ __launch_bounds__(256)
void sq_kernel(const float* __restrict__ X, float* __restrict__ sqws) {
    const int j = blockIdx.x * 256 + threadIdx.x;
    sqws[j] = 0.5f * scan_sq(X + (size_t)j * DIM);   // half-scale scan key
}

__global__ __launch_bounds__(256)
void cvt_kernel(const float* __restrict__ X, unsigned short* __restrict__ Xb) {
    const size_t i = ((size_t)blockIdx.x * 256 + threadIdx.x) * 8;
    const float4 v0 = *(const float4*)(X + i);
    const float4 v1 = *(const float4*)(X + i + 4);
    ushort4 o0, o1;
    o0.x = f2b(v0.x); o0.y = f2b(v0.y); o0.z = f2b(v0.z); o0.w = f2b(v0.w);
    o1.x = f2b(v1.x); o1.y = f2b(v1.y); o1.z = f2b(v1.z); o1.w = f2b(v1.w);
    *(ushort4*)(Xb + i) = o0;
    *(ushort4*)(Xb + i + 4) = o1;
}

// Single-pass packed scan (R25) + row-wide top-RESC prune before rescore:
// 8-way sorted merge picks the 32 best scan keys per row; only those are
// np-exact rescored (4 per scanner thread instead of 18).
__global__ __launch_bounds__(THREADS, 2)
void knn_packed(const float* __restrict__ X, const float* __restrict__ sqws,
                const unsigned short* __restrict__ Xb, int* __restrict__ out) {
    // LDS layout (sequential, 30848 B total):
    //   sk: [RPB][SKSTR] f32 packed scan keys     @ 0      (18560 B)
    //   ci: [RPB][RESC]  u32 chosen indices       @ 18560  ( 4096 B)
    //   ek: [RPB][RESC]  u64 exact rescore keys   @ 22656  ( 8192 B)
    __shared__ __align__(16) char smem[30848];
    float*              sk = (float*)smem;
    unsigned int*       ci = (unsigned int*)(smem + 18560);
    unsigned long long* ek = (unsigned long long*)(smem + 22656);

    const int tid  = threadIdx.x;
    const int w    = tid >> 6;        // wave 0..3
    const int l    = tid & 63;        // lane
    const int lg   = l >> 4;          // lane-group 0..3
    const int l15  = l & 15;
    const int rloc = (w >> 1) * 16 + l15;           // local row 0..31
    const int grow = blockIdx.x * RPB + rloc;       // global query row
    const int colbase = (w & 1) * (NPTS / 2);       // column half
    const int sid = (w & 1) * 4 + lg;               // scanner 0..7

    // ---- B fragments: NEGATED query row (validated R13+) ----
    bf16x8 nb[4];
    {
        const unsigned short* xr = Xb + (size_t)grow * DIM + lg * 8;
        #pragma unroll
        for (int m = 0; m < 4; ++m) {
            union { bf16x8 h; uint4 u; } t;
            t.h = *(const bf16x8*)(xr + m * 32);
            t.u.x ^= 0x80008000u; t.u.y ^= 0x80008000u;
            t.u.z ^= 0x80008000u; t.u.w ^= 0x80008000u;
            nb[m] = t.h;
        }
    }

    // ---- single pass: top-TSEL of packed keys, 2 tiles/iter (R25) ----
    float bv[TSEL];
    #pragma unroll
    for (int k = 0; k < TSEL; ++k) bv[k] = 3.0e38f;
    {
        const unsigned short* ap = Xb + (size_t)(colbase + l15) * DIM + lg * 8;
        #pragma unroll 1
        for (int t = 0; t < NT; t += 2) {
            const int cb = colbase + t * 16;
            const bf16x8 a0 = *(const bf16x8*)(ap);
            const bf16x8 a1 = *(const bf16x8*)(ap + 32);
            const bf16x8 a2 = *(const bf16x8*)(ap + 64);
            const bf16x8 a3 = *(const bf16x8*)(ap + 96);
            const bf16x8 b0 = *(const bf16x8*)(ap + 16 * DIM);
            const bf16x8 b1 = *(const bf16x8*)(ap + 16 * DIM + 32);
            const bf16x8 b2 = *(const bf16x8*)(ap + 16 * DIM + 64);
            const bf16x8 b3 = *(const bf16x8*)(ap + 16 * DIM + 96);
            ap += 32 * DIM;
            f32x4 aA1 = *(const f32x4*)&sqws[cb + lg * 4];
            f32x4 aA2 = {0.f, 0.f, 0.f, 0.f};
            f32x4 aB1 = *(const f32x4*)&sqws[cb + 16 + lg * 4];
            f32x4 aB2 = {0.f, 0.f, 0.f, 0.f};
            aA1 = __builtin_amdgcn_mfma_f32_16x16x32_bf16(a0, nb[0], aA1, 0, 0, 0);
            aA2 = __builtin_amdgcn_mfma_f32_16x16x32_bf16(a2, nb[2], aA2, 0, 0, 0);
            aB1 = __builtin_amdgcn_mfma_f32_16x16x32_bf16(b0, nb[0], aB1, 0, 0, 0);
            aB2 = __builtin_amdgcn_mfma_f32_16x16x32_bf16(b2, nb[2], aB2, 0, 0, 0);
            aA1 = __builtin_amdgcn_mfma_f32_16x16x32_bf16(a1, nb[1], aA1, 0, 0, 0);
            aA2 = __builtin_amdgcn_mfma_f32_16x16x32_bf16(a3, nb[3], aA2, 0, 0, 0);
            aB1 = __builtin_amdgcn_mfma_f32_16x16x32_bf16(b1, nb[1], aB1, 0, 0, 0);
            aB2 = __builtin_amdgcn_mfma_f32_16x16x32_bf16(b3, nb[3], aB2, 0, 0, 0);
            #pragma unroll
            for (int r = 0; r < 4; ++r) {
                const float pA = packkey(aA1[r] + aA2[r], cb + lg * 4 + r);
                MED3_LADDER(bv, pA);
            }
            #pragma unroll
            for (int r = 0; r < 4; ++r) {
                const float pB = packkey(aB1[r] + aB2[r], cb + 16 + lg * 4 + r);
                MED3_LADDER(bv, pB);
            }
        }
    }

    // ---- dump sorted per-scanner packed keys to LDS ----
    #pragma unroll
    for (int k = 0; k < TSEL; ++k)
        sk[rloc * SKSTR + sid * TSEL + k] = bv[k];
    __syncthreads();

    // ---- per-row 8-way sorted merge: pop the RESC smallest scan keys ----
    if (tid < RPB) {
        const int base = tid * SKSTR;
        int head[NSC];
        #pragma unroll
        for (int s2 = 0; s2 < NSC; ++s2) head[s2] = 0;
        for (int m = 0; m < RESC; ++m) {
            float best = 3.0e38f; int bs = 0;
            #pragma unroll
            for (int s2 = 0; s2 < NSC; ++s2) {
                const float v = (head[s2] < TSEL)
                    ? sk[base + s2 * TSEL + head[s2]] : 3.0e38f;
                if (v < best) { best = v; bs = s2; }
            }
            ci[tid * RESC + m] = __float_as_uint(best) & IDXMASK;
            #pragma unroll
            for (int s2 = 0; s2 < NSC; ++s2) head[s2] += (s2 == bs) ? 1 : 0;
        }
    }
    __syncthreads();

    // ---- rescore 4 candidates per scanner thread (np-exact, validated) ----
    float4 xi4[32];
    {
        const float4* xr = (const float4*)(X + (size_t)grow * DIM);
        #pragma unroll
        for (int g = 0; g < 32; ++g) xi4[g] = xr[g];
    }
    const float sqi32 = np_sq_avx512(X + (size_t)grow * DIM);

    #pragma unroll 1
    for (int q = 0; q < RESC / NSC; ++q) {
        const int m = sid * (RESC / NSC) + q;
        const int j = (int)ci[rloc * RESC + m];
        unsigned long long key;
        if (j == grow) {
            key = 0xFFFFFFFFFFFFFFFFULL;              // self: excluded
        } else {
            const float* xjp = X + (size_t)j * DIM;
            const float4* xj = (const float4*)xjp;
            const float sqj32 = np_sq_avx512(xjp);
            float cacc = 0.f;
            #pragma unroll
            for (int g = 0; g < 32; ++g) {
                const float4 a = xi4[g], b = xj[g];
                cacc = __fmaf_rn(a.x, b.x, cacc);
                cacc = __fmaf_rn(a.y, b.y, cacc);
                cacc = __fmaf_rn(a.z, b.z, cacc);
                cacc = __fmaf_rn(a.w, b.w, cacc);
            }
            float d2c = __fsub_rn(__fadd_rn(sqi32, sqj32),
                                  __fmul_rn(2.0f, cacc));
            if (d2c < 0.0f) d2c = 0.0f;
            const float dist32 = sqrtf(d2c);          // f32 sqrt, correct rnd
            key = ((unsigned long long)__float_as_uint(dist32) << 32)
                  | (unsigned int)j;
        }
        ek[rloc * RESC + m] = key;
    }
    __syncthreads();

    // ---- per-row exact top-16 from RESC u64 keys (stable-low) ----
    if (tid < RPB) {
        const int base = tid * RESC;
        const int i = blockIdx.x * RPB + tid;
        for (int m = 0; m < KSEL; ++m) {
            unsigned long long best = 0xFFFFFFFFFFFFFFFFULL; int bc = 0;
            for (int c2 = 0; c2 < RESC; ++c2) {
                const unsigned long long v = ek[base + c2];
                if (v < best) { best = v; bc = c2; }
            }
            out[(size_t)i * KSEL + m] = (int)(best & 0xFFFFFFFFULL);
            ek[base + bc] = 0xFFFFFFFFFFFFFFFFULL;    // remove picked
        }
    }
}

// ---- fallback monolith (R14 verbatim, proven; used only without ws) ----
__global__ __launch_bounds__(THREADS, 2)
void knn_mono(const float* __restrict__ X, int* __restrict__ out) {
    __shared__ __align__(16) char smem[NPTS * 4];
    float* sqh = (float*)smem;
    unsigned long long* keys = (unsigned long long*)smem;
    const int tid = threadIdx.x;
    const int w = tid >> 6, l = tid & 63, lg = l >> 4, l15 = l & 15;
    const int rloc = (w >> 1) * 16 + l15;
    const int grow = blockIdx.x * RPB + rloc;
    const int colbase = (w & 1) * (NPTS / 2);
    const int s = (w & 1) * 4 + lg;
    #pragma unroll 1
    for (int q = 0; q < NPTS / THREADS; ++q) {
        const int j = tid + THREADS * q;
        sqh[j] = 0.5f * scan_sq(X + (size_t)j * DIM);
    }
    __syncthreads();
    bf16x8 nb[4];
    {
        const float* xr = X + (size_t)grow * DIM + lg * 8;
        #pragma unroll
        for (int m = 0; m < 4; ++m) {
            bf16x8 h;
            #pragma unroll
            for (int e = 0; e < 8; ++e) h[e] = (short)f2b(-xr[m * 32 + e]);
            nb[m] = h;
        }
    }
    float bv[TSEL]; int bi[TSEL];
    #pragma unroll
    for (int k = 0; k < TSEL; ++k) { bv[k] = 3.0e38f; bi[k] = 0; }
    const float* apf = X + (size_t)(colbase + l15) * DIM + lg * 8;
    #pragma unroll 1
    for (int t = 0; t < NT; ++t) {
        const int cb = colbase + t * 16;
        bf16x8 a0, a1, a2, a3;
        #pragma unroll
        for (int e = 0; e < 8; ++e) {
            a0[e] = (short)f2b(apf[e]);
            a1[e] = (short)f2b(apf[32 + e]);
            a2[e] = (short)f2b(apf[64 + e]);
            a3[e] = (short)f2b(apf[96 + e]);
        }
        apf += 16 * DIM;
        f32x4 acc = *(const f32x4*)&sqh[cb + lg * 4];
        acc = __builtin_amdgcn_mfma_f32_16x16x32_bf16(a0, nb[0], acc, 0, 0, 0);
        acc = __builtin_amdgcn_mfma_f32_16x16x32_bf16(a1, nb[1], acc, 0, 0, 0);
        acc = __builtin_amdgcn_mfma_f32_16x16x32_bf16(a2, nb[2], acc, 0, 0, 0);
        acc = __builtin_amdgcn_mfma_f32_16x16x32_bf16(a3, nb[3], acc, 0, 0, 0);
        #pragma unroll
        for (int r = 0; r < 4; ++r) {
            const float val = acc[r];
            if (val < bv[TSEL - 1]) {
                const int jg = cb + lg * 4 + r;
                #pragma unroll
                for (int k = TSEL - 1; k >= 1; --k) {
                    const bool m1 = val < bv[k - 1];
                    const bool m2 = val < bv[k];
                    bv[k] = m1 ? bv[k - 1] : (m2 ? val : bv[k]);
                    bi[k] = m1 ? bi[k - 1] : (m2 ? jg  : bi[k]);
                }
                if (val < bv[0]) { bv[0] = val; bi[0] = jg; }
            }
        }
    }
    __syncthreads();
    float4 xi4[32];
    {
        const float4* xr = (const float4*)(X + (size_t)grow * DIM);
        #pragma unroll
        for (int g = 0; g < 32; ++g) xi4[g] = xr[g];
    }
    const float sqi32 = np_sq_avx512(X + (size_t)grow * DIM);
    #pragma unroll
    for (int k = 0; k < TSEL; ++k) {
        const int j = bi[k];
        unsigned long long key;
        if (j == grow) {
            key = 0xFFFFFFFFFFFFFFFFULL;
        } else {
            const float* xjp = X + (size_t)j * DIM;
            const float4* xj = (const float4*)xjp;
            const float sqj32 = np_sq_avx512(xjp);
            float cacc = 0.f;
            #pragma unroll
            for (int g = 0; g < 32; ++g) {
                const float4 a = xi4[g], b = xj[g];
                cacc = __fmaf_rn(a.x, b.x, cacc);
                cacc = __fmaf_rn(a.y, b.y, cacc);
                cacc = __fmaf_rn(a.z, b.z, cacc);
                cacc = __fmaf_rn(a.w, b.w, cacc);
            }
            float d2c = __fsub_rn(__fadd_rn(sqi32, sqj32),
                                  __fmul_rn(2.0f, cacc));
            if (d2c < 0.0f) d2c = 0.0f;
            const float dist32 = sqrtf(d2c);
            key = ((unsigned long long)__float_as_uint(dist32) << 32)
                  | (unsigned int)j;
        }
        keys[rloc * CSTRIDE + s * TSEL + k] = key;
    }
    __syncthreads();
    if (tid < RPB) {
        const int base = tid * CSTRIDE;
        const int i = blockIdx.x * RPB + tid;
        for (int m = 0; m < KSEL; ++m) {
            unsigned long long best = 0xFFFFFFFFFFFFFFFFULL; int bc = 0;
            for (int c2 = 0; c2 < NC; ++c2) {
                const unsigned long long v = keys[base + c2];
                if (v < best) { best = v; bc = c2; }
            }
            out[(size_t)i * KSEL + m] = (int)(best & 0xFFFFFFFFULL);
            keys[base + bc] = 0xFFFFFFFFFFFFFFFFULL;
        }
    }
}

extern "C" void kernel_launch(void* const* d_in, const int* in_sizes, int n_in,
                              void* d_out, int out_size, void* d_ws, size_t ws_size,
                              hipStream_t stream) {
    (void)in_sizes; (void)n_in; (void)out_size;
    const float* X = (const float*)d_in[0];
    int* out = (int*)d_out;
    const size_t WS_NEED = (size_t)NPTS * 4 + (size_t)NPTS * DIM * 2;  // 4.26MB
    if (ws_size >= WS_NEED) {   // proven available R13-R25
        float* sqws = (float*)d_ws;
        unsigned short* Xb = (unsigned short*)((char*)d_ws + (size_t)NPTS * 4);
        sq_kernel<<<dim3(NPTS / 256), dim3(256), 0, stream>>>(X, sqws);
        cvt_kernel<<<dim3(NPTS * DIM / 8 / 256), dim3(256), 0, stream>>>(X, Xb);
        knn_packed<<<dim3(NPTS / RPB), dim3(THREADS), 0, stream>>>(X, sqws, Xb, out);
    } else {
        knn_mono<<<dim3(NPTS / RPB), dim3(THREADS), 0, stream>>>(X, out);
    }
}